// Round 13
// baseline (28.369 us; speedup 1.0000x reference)
//
#include <hip/hip_runtime.h>
#include <hip/hip_bf16.h>

// GATv2 dense complete-graph, B=32, W=128 (in-feat), F=64 (nodes), H=2, D=128.
// R3 structure with rebalanced work split:
// K1: el ONLY (half of R3's work/writes) — x tile in LDS, Wl streamed from L2.
// K2: per (b, i-tile of 8): recomputes er for its 8 rows in-block (cheap,
//     hides in latency slack; bit-identical w-chain), then scores + in-wave
//     softmax + register-tiled aggregate + head-mean. No memset, no atomics.

constexpr int kB = 32, kW = 128, kF = 64, kH = 2, kD = 128, kHD = 256;
constexpr float kNeg = 0.2f;

__device__ __forceinline__ float lrelu(float v) { return fmaxf(v, kNeg * v); }

// ---------------- K1: el projection only ----------------
// grid = B*8 (8 column-slices of 32), block = 512.
__global__ __launch_bounds__(512) void gat_proj_el(
    const float* __restrict__ x, const float* __restrict__ Wl,
    float* __restrict__ elw) {
  __shared__ float xw[kW][kF + 4];
  const int b = blockIdx.x >> 3;
  const int c0 = (blockIdx.x & 7) << 5;
  const int t = threadIdx.x;

  const float* xb = x + b * (kW * kF);
#pragma unroll
  for (int k = 0; k < 16; ++k) {
    const int idx = t + (k << 9);
    xw[idx >> 6][idx & 63] = xb[idx];  // xw[w][n] = x[b][w][n]
  }
  __syncthreads();

  const int c = c0 + (t & 31);
  const int n0 = (t >> 5) << 2;  // 4 rows per thread
  float accl[4] = {0.f, 0.f, 0.f, 0.f};
  const float* wlp = Wl + c;

#pragma unroll 8
  for (int w = 0; w < kW; ++w) {
    const float wl = wlp[w * kHD];  // global, L2-hit, VMEM pipe
    const float4 xa = *(const float4*)&xw[w][n0];
    accl[0] = fmaf(xa.x, wl, accl[0]);
    accl[1] = fmaf(xa.y, wl, accl[1]);
    accl[2] = fmaf(xa.z, wl, accl[2]);
    accl[3] = fmaf(xa.w, wl, accl[3]);
  }

  const int base = (b * kF + n0) * kHD + c;
#pragma unroll
  for (int k = 0; k < 4; ++k) elw[base + k * kHD] = accl[k];
}

// ---------------- K2: attention (both heads per block) ----------------
// grid = B*8 (i-tiles of 8), block = 512.
// u[] union: xw[128][68] (er-recompute phase) then pbuf[4][2][8][132]
// (aggregate partials). 8704 words = 34 KB.
#define XW(w, n) u[(w) * 68 + (n)]
#define PBUF(jq, h, i, d) u[(((jq) * 2 + (h)) * 8 + (i)) * 132 + (d)]

__global__ __launch_bounds__(512) void gat_attn(
    const float* __restrict__ elw, const float* __restrict__ x,
    const float* __restrict__ Wr, const float* __restrict__ attn_a,
    const float* __restrict__ bias, float* __restrict__ out) {
  __shared__ float el[kH][kF][kD + 4];  // 67.6 KB
  __shared__ float er[kH][8][kD + 4];   //  8.4 KB
  __shared__ float av[kH][kD];          //  1 KB
  __shared__ float sAT[kH][kF][8];      //  4 KB (alphas [h][j][i])
  __shared__ float u[8704];             // 34 KB (xw / pbuf union)

  const int b = blockIdx.x >> 3;
  const int i0 = (blockIdx.x & 7) << 3;
  const int t = threadIdx.x;

  // ---- stage: el (both heads, 64 rows) from ws; x[b] transposed; attn_a ----
  {
    const float* elb = elw + b * (kF * kHD);
#pragma unroll
    for (int k = 0; k < 8; ++k) {
      const int s = t + (k << 9);  // 0..4095 float4 slots
      const int h = s >> 11;
      const int n = (s >> 5) & 63;
      const int dv = (s & 31) << 2;
      *(float4*)&el[h][n][dv] = *(const float4*)&elb[n * kHD + h * kD + dv];
    }
    const float* xb = x + b * (kW * kF);
#pragma unroll
    for (int k = 0; k < 16; ++k) {
      const int idx = t + (k << 9);
      XW(idx >> 6, idx & 63) = xb[idx];  // xw[w][n] = x[b][w][n]
    }
    if (t < kH * kD) av[t >> 7][t & 127] = attn_a[t];
  }
  __syncthreads();

  // ---- er recompute (8 dst rows, both heads): wave = row, lane = col ----
  // xs is wave-uniform (LDS broadcast); Wr stream is fully coalesced.
  // Same sequential w-chain as K1 -> bit-identical to R3's er.
  {
    const int i = t >> 6;            // wave index = local row
    const int c4 = (t & 63) << 2;    // 4 cols; spans both heads
    const int n = i0 + i;
    float a[4] = {0.f, 0.f, 0.f, 0.f};
    const float* wrp = Wr + c4;
#pragma unroll 8
    for (int w = 0; w < kW; ++w) {
      const float xs = XW(w, n);
      const float4 w4 = *(const float4*)&wrp[w * kHD];
      a[0] = fmaf(xs, w4.x, a[0]);
      a[1] = fmaf(xs, w4.y, a[1]);
      a[2] = fmaf(xs, w4.z, a[2]);
      a[3] = fmaf(xs, w4.w, a[3]);
    }
    *(float4*)&er[c4 >> 7][i][c4 & 127] = make_float4(a[0], a[1], a[2], a[3]);
  }
  __syncthreads();

  // ---- scores + in-wave softmax ----
  // thread = q(4b) | jh(1b) | i(3b) | h(1b): the 32 threads sharing (h,i)
  // are one aligned 32-lane group -> shfl softmax, no LDS round-trip.
  {
    const int q = t & 15;
    const int jh = (t >> 4) & 1;
    const int i = (t >> 5) & 7;
    const int h = t >> 8;
    const int j0 = q + (jh << 5);  // {0..15} u {32..47}
    const int j1 = j0 + 16;        // {16..31} u {48..63}
    float e0 = 0.f, e1 = 0.f;
#pragma unroll
    for (int dv = 0; dv < kD; dv += 4) {
      const float4 rv = *(const float4*)&er[h][i][dv];
      const float4 a4 = *(const float4*)&av[h][dv];
      const float4 p0 = *(const float4*)&el[h][j0][dv];
      const float4 p1 = *(const float4*)&el[h][j1][dv];
      e0 = fmaf(lrelu(p0.x + rv.x), a4.x, e0);
      e0 = fmaf(lrelu(p0.y + rv.y), a4.y, e0);
      e0 = fmaf(lrelu(p0.z + rv.z), a4.z, e0);
      e0 = fmaf(lrelu(p0.w + rv.w), a4.w, e0);
      e1 = fmaf(lrelu(p1.x + rv.x), a4.x, e1);
      e1 = fmaf(lrelu(p1.y + rv.y), a4.y, e1);
      e1 = fmaf(lrelu(p1.z + rv.z), a4.z, e1);
      e1 = fmaf(lrelu(p1.w + rv.w), a4.w, e1);
    }
    // softmax over the 32-lane (h,i) group; each lane holds 2 of 64 j's
    float m = fmaxf(e0, e1);
#pragma unroll
    for (int off = 1; off < 32; off <<= 1) m = fmaxf(m, __shfl_xor(m, off));
    const float x0 = __expf(e0 - m);
    const float x1 = __expf(e1 - m);
    float s = x0 + x1;
#pragma unroll
    for (int off = 1; off < 32; off <<= 1) s += __shfl_xor(s, off);
    const float inv = 1.f / s;
    sAT[h][j0][i] = x0 * inv;
    sAT[h][j1][i] = x1 * inv;
  }
  __syncthreads();

  // ---- aggregate: thread = h(1b)|jq(2b)|ip(1b)|dq(5b); 4i x 4d tile ----
  // xw is dead; pbuf aliases it.
  {
    const int dq = t & 31;        // d = dq*4 .. +3
    const int ip = (t >> 5) & 1;  // i = ip*4 .. +3
    const int jq = (t >> 6) & 3;  // 16 j's
    const int h = t >> 8;
    float acc[4][4] = {};
    const int jbase = jq << 4;
#pragma unroll
    for (int jj = 0; jj < 16; ++jj) {
      const int j = jbase + jj;
      const float4 al = *(const float4*)&sAT[h][j][ip << 2];
      const float4 ev = *(const float4*)&el[h][j][dq << 2];
      acc[0][0] = fmaf(al.x, ev.x, acc[0][0]);
      acc[0][1] = fmaf(al.x, ev.y, acc[0][1]);
      acc[0][2] = fmaf(al.x, ev.z, acc[0][2]);
      acc[0][3] = fmaf(al.x, ev.w, acc[0][3]);
      acc[1][0] = fmaf(al.y, ev.x, acc[1][0]);
      acc[1][1] = fmaf(al.y, ev.y, acc[1][1]);
      acc[1][2] = fmaf(al.y, ev.z, acc[1][2]);
      acc[1][3] = fmaf(al.y, ev.w, acc[1][3]);
      acc[2][0] = fmaf(al.z, ev.x, acc[2][0]);
      acc[2][1] = fmaf(al.z, ev.y, acc[2][1]);
      acc[2][2] = fmaf(al.z, ev.z, acc[2][2]);
      acc[2][3] = fmaf(al.z, ev.w, acc[2][3]);
      acc[3][0] = fmaf(al.w, ev.x, acc[3][0]);
      acc[3][1] = fmaf(al.w, ev.y, acc[3][1]);
      acc[3][2] = fmaf(al.w, ev.z, acc[3][2]);
      acc[3][3] = fmaf(al.w, ev.w, acc[3][3]);
    }
#pragma unroll
    for (int ii = 0; ii < 4; ++ii) {
      *(float4*)&PBUF(jq, h, (ip << 2) + ii, dq << 2) =
          make_float4(acc[ii][0], acc[ii][1], acc[ii][2], acc[ii][3]);
    }
  }
  __syncthreads();

  // ---- final: sum jq partials + heads, bias, mean, store ----
  {
    const int i = t & 7;
    const int d = (t >> 3) << 1;  // d-pair
    float o0 = 0.f, o1 = 0.f;
#pragma unroll
    for (int jq = 0; jq < 4; ++jq) {
#pragma unroll
      for (int h = 0; h < 2; ++h) {
        const float* p = &PBUF(jq, h, i, d);
        o0 += p[0];
        o1 += p[1];
      }
    }
    const float b0 = bias[d] + bias[kD + d];
    const float b1 = bias[d + 1] + bias[kD + d + 1];
    float* ob = out + b * (kD * kF) + i0 + i;
    ob[d * kF] = 0.5f * (o0 + b0);
    ob[(d + 1) * kF] = 0.5f * (o1 + b1);
  }
}

extern "C" void kernel_launch(void* const* d_in, const int* in_sizes, int n_in,
                              void* d_out, int out_size, void* d_ws,
                              size_t ws_size, hipStream_t stream) {
  (void)in_sizes; (void)n_in; (void)ws_size; (void)out_size;
  const float* x = (const float*)d_in[0];
  const float* Wl = (const float*)d_in[1];
  const float* Wr = (const float*)d_in[2];
  const float* attn_a = (const float*)d_in[3];
  const float* bias = (const float*)d_in[4];
  float* out = (float*)d_out;

  float* elw = (float*)d_ws;  // [B][64][256] = 2 MB (el only)

  gat_proj_el<<<dim3(kB * 8), dim3(512), 0, stream>>>(x, Wl, elw);
  gat_attn<<<dim3(kB * 8), dim3(512), 0, stream>>>(elw, x, Wr, attn_a, bias,
                                                   out);
}

// Round 14
// 24.345 us; speedup vs baseline: 1.1653x; 1.1653x over previous
//
#include <hip/hip_runtime.h>
#include <hip/hip_bf16.h>

// GATv2 dense complete-graph, B=32, W=128 (in-feat), F=64 (nodes), H=2, D=128.
// K1: el/er projection — x tile in LDS (1 b128/iter), W streamed from global.
// K2: per (b, i-tile of 8): scores + in-wave softmax (shfl) + register-blocked
//     aggregate + head-mean, each output written exactly once.
// (R3 configuration — empirical best across 12 structural variants:
//  fusion x3, occupancy x2, work-split x2, shuffle/DS-pipe rebalance x3.)

constexpr int kB = 32, kW = 128, kF = 64, kH = 2, kD = 128, kHD = 256;
constexpr float kNeg = 0.2f;

__device__ __forceinline__ float lrelu(float v) { return fmaxf(v, kNeg * v); }

// ---------------- K1: projection ----------------
// grid = B*8 (8 column-slices of 32), block = 512.
__global__ __launch_bounds__(512) void gat_proj(
    const float* __restrict__ x, const float* __restrict__ Wl,
    const float* __restrict__ Wr, float* __restrict__ elw,
    float* __restrict__ erw) {
  __shared__ float xw[kW][kF + 4];
  const int b = blockIdx.x >> 3;
  const int c0 = (blockIdx.x & 7) << 5;
  const int t = threadIdx.x;

  const float* xb = x + b * (kW * kF);
#pragma unroll
  for (int k = 0; k < 16; ++k) {
    const int idx = t + (k << 9);
    xw[idx >> 6][idx & 63] = xb[idx];  // xw[w][n] = x[b][w][n]
  }
  __syncthreads();

  const int c = c0 + (t & 31);
  const int n0 = (t >> 5) << 2;  // 4 rows per thread
  float accl[4] = {0.f, 0.f, 0.f, 0.f};
  float accr[4] = {0.f, 0.f, 0.f, 0.f};
  const float* wlp = Wl + c;
  const float* wrp = Wr + c;

#pragma unroll 8
  for (int w = 0; w < kW; ++w) {
    const float wl = wlp[w * kHD];   // global, L2-hit, VMEM pipe
    const float wr = wrp[w * kHD];
    const float4 xa = *(const float4*)&xw[w][n0];
    accl[0] = fmaf(xa.x, wl, accl[0]); accr[0] = fmaf(xa.x, wr, accr[0]);
    accl[1] = fmaf(xa.y, wl, accl[1]); accr[1] = fmaf(xa.y, wr, accr[1]);
    accl[2] = fmaf(xa.z, wl, accl[2]); accr[2] = fmaf(xa.z, wr, accr[2]);
    accl[3] = fmaf(xa.w, wl, accl[3]); accr[3] = fmaf(xa.w, wr, accr[3]);
  }

  const int base = (b * kF + n0) * kHD + c;
#pragma unroll
  for (int k = 0; k < 4; ++k) {
    elw[base + k * kHD] = accl[k];
    erw[base + k * kHD] = accr[k];
  }
}

// ---------------- K2: attention (both heads per block) ----------------
// grid = B*8 (i-tiles of 8), block = 512.
__global__ __launch_bounds__(512) void gat_attn(
    const float* __restrict__ elw, const float* __restrict__ erw,
    const float* __restrict__ attn_a, const float* __restrict__ bias,
    float* __restrict__ out) {
  __shared__ float el[kH][kF][kD + 4];     // 67.6 KB
  __shared__ float er[kH][8][kD + 4];      //  8.4 KB
  __shared__ float av[kH][kD];             //  1 KB
  __shared__ float sAT[kH][kF][8];         //  4 KB (alphas [h][j][i])
  __shared__ float pbuf[4][kH][8][kD + 4]; // 33.8 KB (j-quarter partials)

  const int b = blockIdx.x >> 3;
  const int i0 = (blockIdx.x & 7) << 3;
  const int t = threadIdx.x;

  // ---- stage: el (both heads, all 64 src rows), er (8 dst rows), attn_a ----
  {
    const float* elb = elw + b * (kF * kHD);
#pragma unroll
    for (int k = 0; k < 8; ++k) {
      const int s = t + (k << 9);        // 0..4095 float4 slots
      const int h = s >> 11;
      const int n = (s >> 5) & 63;
      const int dv = (s & 31) << 2;
      *(float4*)&el[h][n][dv] = *(const float4*)&elb[n * kHD + h * kD + dv];
    }
    const float* erb = erw + (b * kF + i0) * kHD;
    {
      const int h = t >> 8;
      const int r = (t >> 5) & 7;
      const int dv = (t & 31) << 2;
      *(float4*)&er[h][r][dv] = *(const float4*)&erb[r * kHD + h * kD + dv];
    }
    if (t < kH * kD) av[t >> 7][t & 127] = attn_a[t];
  }
  __syncthreads();

  // ---- scores + in-wave softmax ----
  // thread = q(4b) | jh(1b) | i(3b) | h(1b): the 32 threads sharing (h,i)
  // are one aligned 32-lane group -> shfl softmax, no LDS round-trip.
  {
    const int q = t & 15;
    const int jh = (t >> 4) & 1;
    const int i = (t >> 5) & 7;
    const int h = t >> 8;
    const int j0 = q + (jh << 5);   // {0..15} u {32..47}
    const int j1 = j0 + 16;         // {16..31} u {48..63}
    float e0 = 0.f, e1 = 0.f;
#pragma unroll
    for (int dv = 0; dv < kD; dv += 4) {
      const float4 rv = *(const float4*)&er[h][i][dv];
      const float4 a4 = *(const float4*)&av[h][dv];
      const float4 p0 = *(const float4*)&el[h][j0][dv];
      const float4 p1 = *(const float4*)&el[h][j1][dv];
      e0 = fmaf(lrelu(p0.x + rv.x), a4.x, e0);
      e0 = fmaf(lrelu(p0.y + rv.y), a4.y, e0);
      e0 = fmaf(lrelu(p0.z + rv.z), a4.z, e0);
      e0 = fmaf(lrelu(p0.w + rv.w), a4.w, e0);
      e1 = fmaf(lrelu(p1.x + rv.x), a4.x, e1);
      e1 = fmaf(lrelu(p1.y + rv.y), a4.y, e1);
      e1 = fmaf(lrelu(p1.z + rv.z), a4.z, e1);
      e1 = fmaf(lrelu(p1.w + rv.w), a4.w, e1);
    }
    // softmax over the 32-lane (h,i) group; each lane holds 2 of 64 j's
    float m = fmaxf(e0, e1);
#pragma unroll
    for (int off = 1; off < 32; off <<= 1) m = fmaxf(m, __shfl_xor(m, off));
    const float x0 = __expf(e0 - m);
    const float x1 = __expf(e1 - m);
    float s = x0 + x1;
#pragma unroll
    for (int off = 1; off < 32; off <<= 1) s += __shfl_xor(s, off);
    const float inv = 1.f / s;
    sAT[h][j0][i] = x0 * inv;
    sAT[h][j1][i] = x1 * inv;
  }
  __syncthreads();

  // ---- aggregate: thread = dq(5b) | ip(1b) | jq(2b) | h(1b) ----
  // 4i x 4d register tile; per j: 1 b128 alpha (broadcast) + 1 b128 el.
  {
    const int dq = t & 31;          // d = dq*4 .. +3
    const int ip = (t >> 5) & 1;    // i = ip*4 .. +3
    const int jq = (t >> 6) & 3;    // 16 j's
    const int h = t >> 8;
    float acc[4][4] = {};
    const int jbase = jq << 4;
#pragma unroll
    for (int jj = 0; jj < 16; ++jj) {
      const int j = jbase + jj;
      const float4 al = *(const float4*)&sAT[h][j][ip << 2];
      const float4 ev = *(const float4*)&el[h][j][dq << 2];
      acc[0][0] = fmaf(al.x, ev.x, acc[0][0]);
      acc[0][1] = fmaf(al.x, ev.y, acc[0][1]);
      acc[0][2] = fmaf(al.x, ev.z, acc[0][2]);
      acc[0][3] = fmaf(al.x, ev.w, acc[0][3]);
      acc[1][0] = fmaf(al.y, ev.x, acc[1][0]);
      acc[1][1] = fmaf(al.y, ev.y, acc[1][1]);
      acc[1][2] = fmaf(al.y, ev.z, acc[1][2]);
      acc[1][3] = fmaf(al.y, ev.w, acc[1][3]);
      acc[2][0] = fmaf(al.z, ev.x, acc[2][0]);
      acc[2][1] = fmaf(al.z, ev.y, acc[2][1]);
      acc[2][2] = fmaf(al.z, ev.z, acc[2][2]);
      acc[2][3] = fmaf(al.z, ev.w, acc[2][3]);
      acc[3][0] = fmaf(al.w, ev.x, acc[3][0]);
      acc[3][1] = fmaf(al.w, ev.y, acc[3][1]);
      acc[3][2] = fmaf(al.w, ev.z, acc[3][2]);
      acc[3][3] = fmaf(al.w, ev.w, acc[3][3]);
    }
#pragma unroll
    for (int ii = 0; ii < 4; ++ii) {
      float4 v;
      v.x = acc[ii][0]; v.y = acc[ii][1]; v.z = acc[ii][2]; v.w = acc[ii][3];
      *(float4*)&pbuf[jq][h][(ip << 2) + ii][dq << 2] = v;
    }
  }
  __syncthreads();

  // ---- final: sum jq partials + heads, bias, mean, store ----
  {
    const int i = t & 7;
    const int d = (t >> 3) << 1;    // d-pair
    float o0 = 0.f, o1 = 0.f;
#pragma unroll
    for (int jq = 0; jq < 4; ++jq) {
#pragma unroll
      for (int h = 0; h < 2; ++h) {
        const float2 v = *(const float2*)&pbuf[jq][h][i][d];
        o0 += v.x;
        o1 += v.y;
      }
    }
    const float b0 = bias[d] + bias[kD + d];
    const float b1 = bias[d + 1] + bias[kD + d + 1];
    float* ob = out + b * (kD * kF) + i0 + i;
    ob[d * kF] = 0.5f * (o0 + b0);
    ob[(d + 1) * kF] = 0.5f * (o1 + b1);
  }
}

extern "C" void kernel_launch(void* const* d_in, const int* in_sizes, int n_in,
                              void* d_out, int out_size, void* d_ws,
                              size_t ws_size, hipStream_t stream) {
  (void)in_sizes; (void)n_in; (void)ws_size; (void)out_size;
  const float* x = (const float*)d_in[0];
  const float* Wl = (const float*)d_in[1];
  const float* Wr = (const float*)d_in[2];
  const float* attn_a = (const float*)d_in[3];
  const float* bias = (const float*)d_in[4];
  float* out = (float*)d_out;

  float* elw = (float*)d_ws;                  // [B][64][256]
  float* erw = elw + (size_t)kB * kF * kHD;   // [B][64][256]

  gat_proj<<<dim3(kB * 8), dim3(512), 0, stream>>>(x, Wl, Wr, elw, erw);
  gat_attn<<<dim3(kB * 8), dim3(512), 0, stream>>>(elw, erw, attn_a, bias, out);
}